// Round 6
// baseline (403.011 us; speedup 1.0000x reference)
//
#include <hip/hip_runtime.h>
#include <math.h>

typedef __bf16 bf16;
typedef __bf16 bf16x4 __attribute__((ext_vector_type(4)));
typedef __bf16 bf16x8 __attribute__((ext_vector_type(8)));
typedef float  f32x4  __attribute__((ext_vector_type(4)));

#define HIDDEN 2048
#define NH     16
#define HD     128
#define BATCH  2
#define SEQ    2048
#define MROWS  (BATCH*SEQ)   // 4096
#define NQKV   (3*HIDDEN)    // 6144

// async global->LDS, 16B per lane. LDS dest must be wave-uniform base + lane*16.
__device__ __forceinline__ void async16(const bf16* g, bf16* l) {
  __builtin_amdgcn_global_load_lds(
      (const __attribute__((address_space(1))) void*)g,
      (__attribute__((address_space(3))) void*)l, 16, 0, 0);
}

// ---------------- fused prep: weight transpose+cast (z<4), hs cast + bias concat (z==4) ----
// grid (64,64,5), block (32,8). Replaces 3 launches with 1 (verified -20us in r5).
__global__ __launch_bounds__(256) void prep_kernel(
    const float* __restrict__ hs,
    const float* __restrict__ Wq, const float* __restrict__ Wk,
    const float* __restrict__ Wv, const float* __restrict__ Wo,
    const float* __restrict__ bq, const float* __restrict__ bk,
    const float* __restrict__ bv,
    bf16* __restrict__ Abf, bf16* __restrict__ WtQKV, bf16* __restrict__ WtO,
    float* __restrict__ biasQ) {
  const int z = blockIdx.z;
  if (z < 4) {
    const float* src; bf16* dst;
    switch (z) {
      case 0: src = Wq; dst = WtQKV; break;
      case 1: src = Wk; dst = WtQKV + 2048 * 2048; break;
      case 2: src = Wv; dst = WtQKV + 2 * 2048 * 2048; break;
      default: src = Wo; dst = WtO; break;
    }
    __shared__ float t[32][33];
    int x  = blockIdx.x * 32 + threadIdx.x;
    int y0 = blockIdx.y * 32;
#pragma unroll
    for (int i = 0; i < 32; i += 8)
      t[threadIdx.y + i][threadIdx.x] = src[(size_t)(y0 + threadIdx.y + i) * HIDDEN + x];
    __syncthreads();
    int xo  = blockIdx.y * 32 + threadIdx.x;
    int yo0 = blockIdx.x * 32;
#pragma unroll
    for (int i = 0; i < 32; i += 8)
      dst[(size_t)(yo0 + threadIdx.y + i) * HIDDEN + xo] = (bf16)t[threadIdx.x][threadIdx.y + i];
  } else {
    // cast 2,097,152 float4 of hidden_state -> bf16; 4096 blocks x 512 each
    const int bid = blockIdx.y * 64 + blockIdx.x;
    const int tid = threadIdx.y * 32 + threadIdx.x;
    int base = bid * 512 + tid;
#pragma unroll
    for (int p = 0; p < 2; p++) {
      float4 f = ((const float4*)hs)[base + p * 256];
      bf16x4 o;
      o[0] = (bf16)f.x; o[1] = (bf16)f.y; o[2] = (bf16)f.z; o[3] = (bf16)f.w;
      ((bf16x4*)Abf)[base + p * 256] = o;
    }
    if (bid < 24) {   // bias concat (6144 floats)
      int i = bid * 256 + tid;
      biasQ[i] = (i < 2048) ? bq[i] : (i < 4096 ? bk[i - 2048] : bv[i - 4096]);
    }
  }
}

// ---------------- per-head V transpose: QKV V-part (s,d) -> Vt (bh, d, s) ----------------
__global__ __launch_bounds__(256) void transpose_v_kernel(
    const bf16* __restrict__ QKV, bf16* __restrict__ Vt) {
  __shared__ bf16 t[32][33];
  int bh = blockIdx.z, b = bh >> 4, h = bh & 15;
  const bf16* src = QKV + (size_t)b * SEQ * NQKV + 2 * HIDDEN + h * HD;  // [s][d], stride NQKV
  bf16* dst = Vt + (size_t)bh * HD * SEQ;                                 // [d][s], stride SEQ
  int s0 = blockIdx.x * 32, d0 = blockIdx.y * 32;
#pragma unroll
  for (int i = 0; i < 32; i += 8)
    t[threadIdx.y + i][threadIdx.x] = src[(size_t)(s0 + threadIdx.y + i) * NQKV + d0 + threadIdx.x];
  __syncthreads();
#pragma unroll
  for (int i = 0; i < 32; i += 8)
    dst[(size_t)(d0 + threadIdx.y + i) * SEQ + s0 + threadIdx.x] = t[threadIdx.x][threadIdx.y + i];
}

// ---------------- GEMM: C[M,N] = A[M,K] @ Bt[N,K]^T + bias, bf16 in, fp32 acc ----------------
// PROVEN round-0 structure (888 TF, MfmaUtil 39, conflicts 0): 128x128 tile, BK=64
// (32 KB LDS), 4 waves of 4x4 16x16x32 MFMA, 32 MFMA per barrier-pair.
// r5 lesson: 32x32x16 shape on this same staging/swizzle produced 1.26e7 bank conflicts
// (VALUBusy 47->13, dur +7%) despite -17% matrix-pipe cycles -- the 16-lane-quarter
// rotation below is the only measured-conflict-free read pattern. Do not change shape
// without re-measuring SQ_LDS_BANK_CONFLICT.
// Rotation swizzle for 128B rows: physical chunk pc = (c + (row&7))&7; staging thread at
// physical (crow, ccc) fetches data chunk (ccc - crow)&7 so async16 dest stays tid*16.
template <typename OutT>
__global__ __launch_bounds__(256) void gemm_bt_bias(
    const bf16* __restrict__ A, const bf16* __restrict__ Bt,
    const float* __restrict__ bias, OutT* __restrict__ C, int N, int K) {
  __shared__ bf16 Ash[128 * 64];
  __shared__ bf16 Bsh[128 * 64];
  const int tid = threadIdx.x;
  const int wave = tid >> 6, lane = tid & 63, quad = lane >> 4, l16 = lane & 15;
  const int wm = (wave & 1) * 64, wn = (wave >> 1) * 64;
  const int m0 = blockIdx.x * 128, n0 = blockIdx.y * 128;

  const f32x4 zero4 = {0.f, 0.f, 0.f, 0.f};
  f32x4 acc[4][4];
#pragma unroll
  for (int i = 0; i < 4; i++)
#pragma unroll
    for (int j = 0; j < 4; j++) acc[i][j] = zero4;

  const int crow = tid >> 3, ccc = tid & 7;       // 32 rows/pass, 8 chunks/row
  const int cd = (ccc - crow) & 7;                // data chunk staged at physical ccc
  const int l7 = l16 & 7;

  const bf16* pa[4];
  const bf16* pb[4];
#pragma unroll
  for (int s = 0; s < 4; s++) {
    pa[s] = &A[(size_t)(m0 + s * 32 + crow) * K + cd * 8];
    pb[s] = &Bt[(size_t)(n0 + s * 32 + crow) * K + cd * 8];
  }

  for (int kt = 0; kt < K; kt += 64) {
    __syncthreads();
#pragma unroll
    for (int s = 0; s < 4; s++) {
      async16(pa[s], &Ash[s * 2048 + tid * 8]);
      async16(pb[s], &Bsh[s * 2048 + tid * 8]);
      pa[s] += 64; pb[s] += 64;
    }
    __syncthreads();

#pragma unroll
    for (int kk = 0; kk < 2; kk++) {
      const int pc = (kk * 4 + quad + l7) & 7;    // physical chunk (un-rotate)
      bf16x8 af[4], bfr[4];
#pragma unroll
      for (int i = 0; i < 4; i++) af[i]  = *(const bf16x8*)&Ash[(wm + i * 16 + l16) * 64 + pc * 8];
#pragma unroll
      for (int j = 0; j < 4; j++) bfr[j] = *(const bf16x8*)&Bsh[(wn + j * 16 + l16) * 64 + pc * 8];
#pragma unroll
      for (int i = 0; i < 4; i++)
#pragma unroll
        for (int j = 0; j < 4; j++)
          acc[i][j] = __builtin_amdgcn_mfma_f32_16x16x32_bf16(af[i], bfr[j], acc[i][j], 0, 0, 0);
    }
  }

  // C/D layout: col = lane&15, row = quad*4 + reg
#pragma unroll
  for (int i = 0; i < 4; i++)
#pragma unroll
    for (int j = 0; j < 4; j++) {
      int n = n0 + wn + j * 16 + l16;
      float bv = bias[n];
#pragma unroll
      for (int r = 0; r < 4; r++) {
        int m = m0 + wm + i * 16 + quad * 4 + r;
        C[(size_t)m * N + n] = (OutT)(acc[i][j][r] + bv);
      }
    }
}

// ---------------- flash attention, double-buffered K/V (r3 version, verified) ----------------
#define KTS   64

__global__ __launch_bounds__(256, 2) void flash_attn_kernel(
    const bf16* __restrict__ QKV, const bf16* __restrict__ Vt, bf16* __restrict__ O) {
  // XCD-aware swizzle of the 512-block grid (16 q-blocks x 32 bh)
  const int fid = blockIdx.x + 16 * blockIdx.y;
  const int nid = (fid & 7) * 64 + (fid >> 3);   // XCD x owns bh 4x..4x+3, all q-blocks
  const int bh = nid >> 4, b = bh >> 4, h = bh & 15;
  const int q0 = (nid & 15) * 128;
  const int tid = threadIdx.x, wave = tid >> 6, lane = tid & 63, quad = lane >> 4, l16 = lane & 15;

  const bf16* Qb  = QKV + (size_t)b * SEQ * NQKV + h * HD;            // Q[s][d], stride NQKV
  const bf16* Kb  = QKV + (size_t)b * SEQ * NQKV + HIDDEN + h * HD;   // K[s][d], stride NQKV
  const bf16* Vtb = Vt + (size_t)bh * HD * SEQ;                       // Vt[d][s], stride SEQ

  __shared__ bf16 Ksh[2][KTS * HD];  // [key][d], swizzled chunks, 2 x 16 KB
  __shared__ bf16 Vsh[2][HD * KTS];  // [d][key], swizzled chunks, 2 x 16 KB
  __shared__ bf16 Psh[128 * 64];     // [q][key], XOR-swizzled, 16 KB

  const int qrow = q0 + wave * 32;
  const float sc = 0.08838834764831845f * 1.44269504088896340f;  // 1/sqrt(128) * log2(e)

  // Q fragments (B-operand; lane layout as before), pre-scaled by sc
  bf16x8 qf[2][4];
#pragma unroll
  for (int mt = 0; mt < 2; mt++)
#pragma unroll
    for (int kk = 0; kk < 4; kk++) {
      bf16x8 t = *(const bf16x8*)&Qb[(size_t)(qrow + mt * 16 + l16) * NQKV + kk * 32 + quad * 8];
#pragma unroll
      for (int j = 0; j < 8; j++) t[j] = (bf16)((float)t[j] * sc);
      qf[mt][kk] = t;
    }

  const f32x4 zero4 = {0.f, 0.f, 0.f, 0.f};
  f32x4 oacc[2][8];
#pragma unroll
  for (int mt = 0; mt < 2; mt++)
#pragma unroll
    for (int nt = 0; nt < 8; nt++) oacc[mt][nt] = zero4;

  float lrun[2] = {0.f, 0.f};   // per-lane: l for q = qrow + mt*16 + l16

  const int krp = tid >> 4, kpp = tid & 15;  // K staging: physical row/chunk
  const int vrp = tid >> 3, vpp = tid & 7;   // V staging
  const int l7 = l16 & 7;

  // hoisted staging pointers (global side carries the rotation pre-swizzle)
  const bf16* pk[4];
  const bf16* pv[4];
#pragma unroll
  for (int s = 0; s < 4; s++) {
    int r  = s * 16 + krp;
    pk[s] = &Kb[(size_t)r * NQKV + (kpp ^ (r & 7)) * 8];
    int rv = s * 32 + vrp;
    pv[s] = &Vtb[(size_t)rv * SEQ + (vpp ^ (rv & 7)) * 8];
  }

  // ---- prologue: stage tile 0 into buf 0 ----
#pragma unroll
  for (int s = 0; s < 4; s++) {
    async16(pk[s], &Ksh[0][s * 2048 + tid * 8]);
    async16(pv[s], &Vsh[0][s * 2048 + tid * 8]);
    pk[s] += (size_t)KTS * NQKV;
    pv[s] += KTS;
  }

  const int NT = SEQ / KTS;   // 32
  for (int t = 0; t < NT; ++t) {
    const int cur = t & 1;
    if (t + 1 < NT) {
#pragma unroll
      for (int s = 0; s < 4; s++) {
        async16(pk[s], &Ksh[cur ^ 1][s * 2048 + tid * 8]);
        async16(pv[s], &Vsh[cur ^ 1][s * 2048 + tid * 8]);
        pk[s] += (size_t)KTS * NQKV;
        pv[s] += KTS;
      }
      asm volatile("s_waitcnt vmcnt(8)" ::: "memory");  // oldest 8 = tile t landed
    } else {
      asm volatile("s_waitcnt vmcnt(0)" ::: "memory");
    }
    __builtin_amdgcn_s_barrier();  // every wave's tile-t loads landed -> LDS consistent

    // S^T = K @ Qs^T : C col = l16 = q, row = quad*4+r = key
    f32x4 st[2][4];
#pragma unroll
    for (int mt = 0; mt < 2; mt++)
#pragma unroll
      for (int nt = 0; nt < 4; nt++) st[mt][nt] = zero4;
#pragma unroll
    for (int kk = 0; kk < 4; kk++) {
      const int p = (4 * kk + quad) ^ l7;   // physical chunk (un-swizzle)
      bf16x8 kf[4];
#pragma unroll
      for (int nt = 0; nt < 4; nt++)
        kf[nt] = *(const bf16x8*)&Ksh[cur][(nt * 16 + l16) * HD + p * 8];
      __builtin_amdgcn_s_setprio(1);
#pragma unroll
      for (int mt = 0; mt < 2; mt++)
#pragma unroll
        for (int nt = 0; nt < 4; nt++)
          st[mt][nt] = __builtin_amdgcn_mfma_f32_16x16x32_bf16(kf[nt], qf[mt][kk], st[mt][nt], 0, 0, 0);
      __builtin_amdgcn_s_setprio(0);
    }

    // p = exp2(s); packed b64 P-write (4 consecutive keys of one q, XOR-swizzled);
    // lane-local sums. P rows are wave-private: no barrier needed before PV.
    float rs[2] = {0.f, 0.f};
#pragma unroll
    for (int mt = 0; mt < 2; mt++)
#pragma unroll
      for (int nt = 0; nt < 4; nt++) {
        bf16x4 pk4;
#pragma unroll
        for (int r = 0; r < 4; r++) {
          float p = exp2f(st[mt][nt][r]);
          rs[mt] += p;
          pk4[r] = (bf16)p;
        }
        int pbyte = ((wave * 32 + mt * 16 + l16) * 64 + nt * 16 + quad * 4) * 2;
        pbyte ^= (l16 & 7) << 4;
        *(bf16x4*)((char*)Psh + pbyte) = pk4;
      }
#pragma unroll
    for (int mt = 0; mt < 2; mt++) {
      float t2 = rs[mt];
      t2 += __shfl_xor(t2, 16);
      t2 += __shfl_xor(t2, 32);
      lrun[mt] += t2;
    }

    // O += P @ V  (P rows are this wave's own rows)
#pragma unroll
    for (int kk2 = 0; kk2 < 2; kk2++) {
      bf16x8 pf[2], vf[8];
#pragma unroll
      for (int mt = 0; mt < 2; mt++) {
        int pbyte = ((wave * 32 + mt * 16 + l16) * 64 + kk2 * 32 + quad * 8) * 2;
        pbyte ^= (l16 & 7) << 4;
        pf[mt] = *(const bf16x8*)((char*)Psh + pbyte);
      }
#pragma unroll
      for (int nt = 0; nt < 8; nt++) {
        int p = (4 * kk2 + quad) ^ l7;  // physical chunk (un-swizzle)
        vf[nt] = *(const bf16x8*)&Vsh[cur][(nt * 16 + l16) * KTS + p * 8];
      }
      __builtin_amdgcn_s_setprio(1);
#pragma unroll
      for (int mt = 0; mt < 2; mt++)
#pragma unroll
        for (int nt = 0; nt < 8; nt++)
          oacc[mt][nt] = __builtin_amdgcn_mfma_f32_16x16x32_bf16(pf[mt], vf[nt], oacc[mt][nt], 0, 0, 0);
      __builtin_amdgcn_s_setprio(0);
    }

    __builtin_amdgcn_s_barrier();  // all waves done reading tile t -> buf free for t+2
  }

  // epilogue: O[q][h*128+d] = oacc / l.  l for q=mt*16+x lives at lanes with l16=x.
#pragma unroll
  for (int mt = 0; mt < 2; mt++) {
    float inv[4];
#pragma unroll
    for (int r = 0; r < 4; r++)
      inv[r] = 1.0f / __shfl(lrun[mt], (lane & 48) | (quad * 4 + r));
#pragma unroll
    for (int nt = 0; nt < 8; nt++)
#pragma unroll
      for (int r = 0; r < 4; r++) {
        int q = qrow + mt * 16 + quad * 4 + r;
        int d = nt * 16 + l16;
        O[(size_t)(b * SEQ + q) * HIDDEN + h * HD + d] = (bf16)(oacc[mt][nt][r] * inv[r]);
      }
  }
}

extern "C" void kernel_launch(void* const* d_in, const int* in_sizes, int n_in,
                              void* d_out, int out_size, void* d_ws, size_t ws_size,
                              hipStream_t stream) {
  const float* hs = (const float*)d_in[0];
  const float* Wq = (const float*)d_in[1];
  const float* bq = (const float*)d_in[2];
  const float* Wk = (const float*)d_in[3];
  const float* bk = (const float*)d_in[4];
  const float* Wv = (const float*)d_in[5];
  const float* bv = (const float*)d_in[6];
  const float* Wo = (const float*)d_in[7];
  const float* bo = (const float*)d_in[8];
  float* out = (float*)d_out;

  char* ws = (char*)d_ws;
  bf16*  Abf   = (bf16*)(ws);                    // 4096*2048*2   = 16,777,216
  bf16*  WtQKV = (bf16*)(ws + 16777216);         // 6144*2048*2   = 25,165,824
  bf16*  WtO   = (bf16*)(ws + 41943040);         // 2048*2048*2   =  8,388,608
  float* biasQ = (float*)(ws + 50331648);        // 6144*4        =     24,576
  bf16*  QKV   = (bf16*)(ws + 50356224);         // 4096*6144*2   = 50,331,648
  bf16*  VT    = (bf16*)(ws + 100687872);        // 32*128*2048*2 = 16,777,216
  bf16*  Obf   = (bf16*)(ws + 117465088);        // 4096*2048*2   = 16,777,216
  // total 134,242,304 bytes of d_ws

  dim3 tb(32, 8);
  // fused prep: weight transposes (z<4) + hs cast + bias concat (z==4)
  prep_kernel<<<dim3(64, 64, 5), tb, 0, stream>>>(
      hs, Wq, Wk, Wv, Wo, bq, bk, bv,
      Abf, WtQKV, WtO, biasQ);

  gemm_bt_bias<bf16><<<dim3(32, 48), 256, 0, stream>>>(Abf, WtQKV, biasQ, QKV, NQKV, HIDDEN);
  transpose_v_kernel<<<dim3(64, 4, 32), tb, 0, stream>>>(QKV, VT);
  flash_attn_kernel<<<dim3(16, 32), 256, 0, stream>>>(QKV, VT, Obf);
  gemm_bt_bias<float><<<dim3(32, 16), 256, 0, stream>>>(Obf, WtO, bo, out, HIDDEN, HIDDEN);
}